// Round 3
// baseline (4414.047 us; speedup 1.0000x reference)
//
#include <hip/hip_runtime.h>
#include <hip/hip_bf16.h>
#include <math.h>

typedef _Float16 f16x4 __attribute__((ext_vector_type(4)));
typedef _Float16 f16x8 __attribute__((ext_vector_type(8)));
typedef float    f32x4 __attribute__((ext_vector_type(4)));
typedef long long LL;

// ---------------------------------------------------------------------------
// embed: x[row, :] = emb[tok[row]] * sqrt(D) + sinusoidal_pe(row % S)
// pe[s, 2j] = sin((s+1)*10000^{-(j+1)/D}), pe[s, 2j+1] = cos(same)
// ---------------------------------------------------------------------------
__global__ __launch_bounds__(256) void embed_kernel(
    float* __restrict__ x, const int* __restrict__ tok,
    const float* __restrict__ emb, int S)
{
  int row = blockIdx.x;                 // 0 .. B*S-1
  int s   = row % S;
  LL  t   = tok[row];
  #pragma unroll
  for (int i = 0; i < 2; i++) {
    int d = threadIdx.x + i * 256;      // 0..511
    int j = d >> 1;                     // 0..255
    float omega = (float)(j + 1) * (1.0f / 512.0f);
    float w = (float)(s + 1) * powf(10000.0f, -omega);
    float pe = (d & 1) ? cosf(w) : sinf(w);
    x[(LL)row * 512 + d] = emb[t * 512 + d] * 22.62741699796952f + pe;
  }
}

// ---------------------------------------------------------------------------
// masked softmax over rows of length 384; one wave per row, 4 rows/block.
// causal: row q only attends k <= q (q = row % 384); masked slots -> 0.
// ---------------------------------------------------------------------------
__global__ __launch_bounds__(256) void softmax_kernel(float* __restrict__ p, int causal)
{
  int lane = threadIdx.x & 63;
  LL row = (LL)blockIdx.x * 4 + (threadIdx.x >> 6);
  int q = (int)(row % 384);
  float* pr = p + row * 384;
  int kmax = causal ? q + 1 : 384;
  float v[6];
  float m = -1e30f;
  #pragma unroll
  for (int i = 0; i < 6; i++) {
    int k = lane + i * 64;
    v[i] = pr[k];
    if (k < kmax) m = fmaxf(m, v[i]);
  }
  #pragma unroll
  for (int o = 32; o > 0; o >>= 1) m = fmaxf(m, __shfl_xor(m, o));
  float s = 0.f;
  #pragma unroll
  for (int i = 0; i < 6; i++) {
    int k = lane + i * 64;
    float e = (k < kmax) ? __expf(v[i] - m) : 0.f;
    v[i] = e; s += e;
  }
  #pragma unroll
  for (int o = 32; o > 0; o >>= 1) s += __shfl_xor(s, o);
  float inv = 1.f / s;
  #pragma unroll
  for (int i = 0; i < 6; i++) pr[lane + i * 64] = v[i] * inv;
}

// ---------------------------------------------------------------------------
// x = LayerNorm(x + d) * g + b, rows of 512; one wave per row, 4 rows/block.
// ---------------------------------------------------------------------------
__global__ __launch_bounds__(256) void ln_kernel(
    float* __restrict__ x, const float* __restrict__ d,
    const float* __restrict__ g, const float* __restrict__ b)
{
  int lane = threadIdx.x & 63;
  LL row = (LL)blockIdx.x * 4 + (threadIdx.x >> 6);
  float* xr = x + row * 512;
  const float* dr = d + row * 512;
  float v[8];
  float s = 0.f;
  #pragma unroll
  for (int i = 0; i < 2; i++) {
    float4 a = *(const float4*)(xr + (LL)(lane + i * 64) * 4);
    float4 e = *(const float4*)(dr + (LL)(lane + i * 64) * 4);
    v[i*4+0] = a.x + e.x; v[i*4+1] = a.y + e.y;
    v[i*4+2] = a.z + e.z; v[i*4+3] = a.w + e.w;
    s += v[i*4+0] + v[i*4+1] + v[i*4+2] + v[i*4+3];
  }
  #pragma unroll
  for (int o = 32; o > 0; o >>= 1) s += __shfl_xor(s, o);
  float mean = s * (1.f / 512.f);
  float q = 0.f;
  #pragma unroll
  for (int i = 0; i < 8; i++) { float t = v[i] - mean; q += t * t; }
  #pragma unroll
  for (int o = 32; o > 0; o >>= 1) q += __shfl_xor(q, o);
  float rstd = rsqrtf(q * (1.f / 512.f) + 1e-5f);
  #pragma unroll
  for (int i = 0; i < 2; i++) {
    float4 gv = *(const float4*)(g + (LL)(lane + i * 64) * 4);
    float4 bv = *(const float4*)(b + (LL)(lane + i * 64) * 4);
    float4 o4;
    o4.x = (v[i*4+0] - mean) * rstd * gv.x + bv.x;
    o4.y = (v[i*4+1] - mean) * rstd * gv.y + bv.y;
    o4.z = (v[i*4+2] - mean) * rstd * gv.z + bv.z;
    o4.w = (v[i*4+3] - mean) * rstd * gv.w + bv.w;
    *(float4*)(xr + (LL)(lane + i * 64) * 4) = o4;
  }
}

// ---------------------------------------------------------------------------
// Batched GEMM: C = act(scale * (A @ B) + bias)
//   A: [M,K] f32, leading dim lda
//   B: bNK=0: [K,N] (ldb over k)   bNK=1: [N,K] (ldb over n; i.e. C = A@B^T)
//   batching: zb = z/zdiv, zh = z%zdiv; each base ptr += zb*s?b + zh*s?h
// Tile 64x64x64; 4 waves in 2x2; each wave 32x32 via 2x2 mfma_f32_16x16x32_f16.
// M,N,K must be multiples of 64 (holds for every call site).
// Fragment layout (verified CDNA4): A/B lane&15 = row/col, k = 8*(lane>>4)+e
// contiguous; C/D: col = lane&15, row = (lane>>4)*4 + reg.
// ---------------------------------------------------------------------------
__global__ __launch_bounds__(256) void gemm_kernel(
    const float* __restrict__ A, const float* __restrict__ B,
    const float* __restrict__ bias, float* __restrict__ C,
    int M, int N, int K, int lda, int ldb, int ldc,
    int zdiv, LL sAb, LL sAh, LL sBb, LL sBh, LL sCb, LL sCh, LL sBiasb,
    float scale, int relu, int bNK)
{
  __shared__ __align__(16) _Float16 As[64][72];   // [m][k], +8 pad
  __shared__ __align__(16) _Float16 Bs[64][72];   // [n][k], +8 pad

  int z  = blockIdx.z;
  int zb = z / zdiv, zh = z - zb * zdiv;
  A += zb * sAb + zh * sAh;
  B += zb * sBb + zh * sBh;
  C += zb * sCb + zh * sCh;
  if (bias) bias += zb * sBiasb;

  int tid  = threadIdx.x;
  int lane = tid & 63, wave = tid >> 6;
  int wr = wave >> 1, wc = wave & 1;          // 2x2 wave grid
  int m0 = blockIdx.y * 64, n0 = blockIdx.x * 64;
  int lr = lane & 15, lg = lane >> 4;

  f32x4 acc[2][2] = {};

  for (int k0 = 0; k0 < K; k0 += 64) {
    // ---- stage A (64x64) and B (64x64) into LDS as f16 ----
    #pragma unroll
    for (int i = 0; i < 4; i++) {
      int idx = tid + i * 256;                // 0..1023, 4 elems each
      int r = idx >> 4, c = (idx & 15) << 2;  // r: 0..63, c: 0..60 step 4
      float4 va = *(const float4*)(A + (LL)(m0 + r) * lda + (k0 + c));
      f16x4 wa = { (_Float16)va.x, (_Float16)va.y, (_Float16)va.z, (_Float16)va.w };
      *(f16x4*)&As[r][c] = wa;
      if (bNK) {
        float4 vb = *(const float4*)(B + (LL)(n0 + r) * ldb + (k0 + c));
        f16x4 wb = { (_Float16)vb.x, (_Float16)vb.y, (_Float16)vb.z, (_Float16)vb.w };
        *(f16x4*)&Bs[r][c] = wb;
      } else {
        float4 vb = *(const float4*)(B + (LL)(k0 + r) * ldb + (n0 + c));
        Bs[c + 0][r] = (_Float16)vb.x;
        Bs[c + 1][r] = (_Float16)vb.y;
        Bs[c + 2][r] = (_Float16)vb.z;
        Bs[c + 3][r] = (_Float16)vb.w;
      }
    }
    __syncthreads();
    // ---- compute: 2 K-chunks of 32, 2x2 fragments ----
    #pragma unroll
    for (int ks = 0; ks < 2; ks++) {
      int kk = ks * 32 + lg * 8;
      f16x8 a0 = *(const f16x8*)&As[wr * 32 + lr][kk];
      f16x8 a1 = *(const f16x8*)&As[wr * 32 + 16 + lr][kk];
      f16x8 b0 = *(const f16x8*)&Bs[wc * 32 + lr][kk];
      f16x8 b1 = *(const f16x8*)&Bs[wc * 32 + 16 + lr][kk];
      acc[0][0] = __builtin_amdgcn_mfma_f32_16x16x32_f16(a0, b0, acc[0][0], 0, 0, 0);
      acc[0][1] = __builtin_amdgcn_mfma_f32_16x16x32_f16(a0, b1, acc[0][1], 0, 0, 0);
      acc[1][0] = __builtin_amdgcn_mfma_f32_16x16x32_f16(a1, b0, acc[1][0], 0, 0, 0);
      acc[1][1] = __builtin_amdgcn_mfma_f32_16x16x32_f16(a1, b1, acc[1][1], 0, 0, 0);
    }
    __syncthreads();
  }

  // ---- epilogue: scale, bias, relu, scalar f32 stores ----
  #pragma unroll
  for (int mf = 0; mf < 2; mf++) {
    #pragma unroll
    for (int nf = 0; nf < 2; nf++) {
      int col = n0 + wc * 32 + nf * 16 + lr;
      float bv = bias ? bias[col] : 0.f;
      int row = m0 + wr * 32 + mf * 16 + lg * 4;
      #pragma unroll
      for (int j = 0; j < 4; j++) {
        float val = acc[mf][nf][j] * scale + bv;
        if (relu) val = fmaxf(val, 0.f);
        C[(LL)(row + j) * ldc + col] = val;
      }
    }
  }
}

// ---------------------------------------------------------------------------
// host-side launcher
// ---------------------------------------------------------------------------
static inline void gemm(hipStream_t st,
    const float* A, const float* Bm, const float* bias, float* C,
    int M, int N, int K, int lda, int ldb, int ldc,
    int Z, int zdiv, LL sAb, LL sAh, LL sBb, LL sBh, LL sCb, LL sCh, LL sBias,
    float scale, int relu, int bNK)
{
  dim3 g(N / 64, M / 64, Z);
  gemm_kernel<<<g, 256, 0, st>>>(A, Bm, bias, C, M, N, K, lda, ldb, ldc,
                                 zdiv, sAb, sAh, sBb, sBh, sCb, sCh, sBias,
                                 scale, relu, bNK);
}

extern "C" void kernel_launch(void* const* d_in, const int* in_sizes, int n_in,
                              void* d_out, int out_size, void* d_ws, size_t ws_size,
                              hipStream_t stream)
{
  (void)in_sizes; (void)n_in; (void)out_size; (void)ws_size;
  const int*   src     = (const int*)d_in[0];
  const int*   tgt     = (const int*)d_in[1];
  const float* src_emb = (const float*)d_in[2];
  const float* tgt_emb = (const float*)d_in[3];
  const float* eaw = (const float*)d_in[4];
  const float* eab = (const float*)d_in[5];
  const float* ef1 = (const float*)d_in[6];
  const float* eb1 = (const float*)d_in[7];
  const float* ef2 = (const float*)d_in[8];
  const float* eb2 = (const float*)d_in[9];
  const float* elg = (const float*)d_in[10];
  const float* elb = (const float*)d_in[11];
  const float* dmw = (const float*)d_in[12];
  const float* dmb = (const float*)d_in[13];
  const float* dsw = (const float*)d_in[14];
  const float* dsb = (const float*)d_in[15];
  const float* df1 = (const float*)d_in[16];
  const float* db1 = (const float*)d_in[17];
  const float* df2 = (const float*)d_in[18];
  const float* db2 = (const float*)d_in[19];
  const float* dlg = (const float*)d_in[20];
  const float* dlb = (const float*)d_in[21];
  float* out = (float*)d_out;

  const int Bb = 4, S = 384, D = 512, H = 8, F = 2048, Lc = 6, V = 32000;
  const int Mr = Bb * S;                 // 1536
  const LL  NX = (LL)Mr * D;             // 786432
  const LL  DD = (LL)D * D;              // 262144
  const LL  SD = (LL)S * D;              // 196608
  const LL  SS = (LL)S * S;              // 147456

  float* ws  = (float*)d_ws;
  float* x   = ws;                       // encoder state / memory   [Mr,D]
  float* y   = x + NX;                   // decoder state            [Mr,D]
  float* qkv = y + NX;                   // q,k,v                    [3,Mr,D]
  float* sc  = qkv + 3 * NX;             // scores [B,H,S,S] / ff-mid [Mr,F]
  float* t0  = sc + 6 * NX;              // attn PV output           [Mr,D]
  float* t1  = t0 + NX;                  // projection output        [Mr,D]

  // ---------------- encoder ----------------
  embed_kernel<<<Mr, 256, 0, stream>>>(x, src, src_emb, S);
  for (int i = 0; i < Lc; i++) {
    const float* W   = eaw + (LL)i * 4 * DD;
    const float* bia = eab + (LL)i * 4 * D;
    // q,k,v projections (z over the 3 weight slices)
    gemm(stream, x, W, bia, qkv, Mr, 512, 512, 512, 512, 512,
         3, 1, 0, 0, DD, 0, NX, 0, D, 1.f, 0, 0);
    // scores = q @ k^T / 8   (z over B*H)
    gemm(stream, qkv, qkv + NX, nullptr, sc, S, S, 64, 512, 512, S,
         32, H, SD, 64, SD, 64, (LL)H * SS, SS, 0, 0.125f, 0, 1);
    softmax_kernel<<<(Bb * H * S) / 4, 256, 0, stream>>>(sc, 1);  // causal (enc quirk)
    // t0 = P @ v
    gemm(stream, sc, qkv + 2 * NX, nullptr, t0, S, 64, S, S, 512, 512,
         32, H, (LL)H * SS, SS, SD, 64, SD, 64, 0, 1.f, 0, 0);
    // o-projection
    gemm(stream, t0, W + 3 * DD, bia + 3 * D, t1, Mr, 512, 512, 512, 512, 512,
         1, 1, 0, 0, 0, 0, 0, 0, 0, 1.f, 0, 0);
    ln_kernel<<<Mr / 4, 256, 0, stream>>>(x, t1, elg, elb);
    // ff (relu after BOTH linears)
    gemm(stream, x, ef1 + (LL)i * D * F, eb1 + (LL)i * F, sc, Mr, F, 512, 512, F, F,
         1, 1, 0, 0, 0, 0, 0, 0, 0, 1.f, 1, 0);
    gemm(stream, sc, ef2 + (LL)i * F * D, eb2 + (LL)i * D, t1, Mr, 512, F, F, 512, 512,
         1, 1, 0, 0, 0, 0, 0, 0, 0, 1.f, 1, 0);
    ln_kernel<<<Mr / 4, 256, 0, stream>>>(x, t1, elg, elb);
  }

  // ---------------- decoder ----------------
  embed_kernel<<<Mr, 256, 0, stream>>>(y, tgt, tgt_emb, S);
  for (int i = 0; i < Lc; i++) {
    // --- memory attention (not causal): q from y, k/v from enc(x) ---
    const float* Wm = dmw + (LL)i * 4 * DD;
    const float* bm = dmb + (LL)i * 4 * D;
    gemm(stream, y, Wm, bm, qkv, Mr, 512, 512, 512, 512, 512,
         1, 1, 0, 0, 0, 0, 0, 0, 0, 1.f, 0, 0);
    gemm(stream, x, Wm + DD, bm + D, qkv + NX, Mr, 512, 512, 512, 512, 512,
         2, 1, 0, 0, DD, 0, NX, 0, D, 1.f, 0, 0);
    gemm(stream, qkv, qkv + NX, nullptr, sc, S, S, 64, 512, 512, S,
         32, H, SD, 64, SD, 64, (LL)H * SS, SS, 0, 0.125f, 0, 1);
    softmax_kernel<<<(Bb * H * S) / 4, 256, 0, stream>>>(sc, 0);
    gemm(stream, sc, qkv + 2 * NX, nullptr, t0, S, 64, S, S, 512, 512,
         32, H, (LL)H * SS, SS, SD, 64, SD, 64, 0, 1.f, 0, 0);
    gemm(stream, t0, Wm + 3 * DD, bm + 3 * D, t1, Mr, 512, 512, 512, 512, 512,
         1, 1, 0, 0, 0, 0, 0, 0, 0, 1.f, 0, 0);
    ln_kernel<<<Mr / 4, 256, 0, stream>>>(y, t1, dlg, dlb);
    // --- self attention (causal) ---
    const float* Ws = dsw + (LL)i * 4 * DD;
    const float* bs = dsb + (LL)i * 4 * D;
    gemm(stream, y, Ws, bs, qkv, Mr, 512, 512, 512, 512, 512,
         3, 1, 0, 0, DD, 0, NX, 0, D, 1.f, 0, 0);
    gemm(stream, qkv, qkv + NX, nullptr, sc, S, S, 64, 512, 512, S,
         32, H, SD, 64, SD, 64, (LL)H * SS, SS, 0, 0.125f, 0, 1);
    softmax_kernel<<<(Bb * H * S) / 4, 256, 0, stream>>>(sc, 1);
    gemm(stream, sc, qkv + 2 * NX, nullptr, t0, S, 64, S, S, 512, 512,
         32, H, (LL)H * SS, SS, SD, 64, SD, 64, 0, 1.f, 0, 0);
    gemm(stream, t0, Ws + 3 * DD, bs + 3 * D, t1, Mr, 512, 512, 512, 512, 512,
         1, 1, 0, 0, 0, 0, 0, 0, 0, 1.f, 0, 0);
    ln_kernel<<<Mr / 4, 256, 0, stream>>>(y, t1, dlg, dlb);
    // --- ff ---
    gemm(stream, y, df1 + (LL)i * D * F, db1 + (LL)i * F, sc, Mr, F, 512, 512, F, F,
         1, 1, 0, 0, 0, 0, 0, 0, 0, 1.f, 1, 0);
    gemm(stream, sc, df2 + (LL)i * F * D, db2 + (LL)i * D, t1, Mr, 512, F, F, 512, 512,
         1, 1, 0, 0, 0, 0, 0, 0, 0, 1.f, 1, 0);
    ln_kernel<<<Mr / 4, 256, 0, stream>>>(y, t1, dlg, dlb);
  }

  // ---------------- unembed: out = y @ tgt_emb^T ----------------
  gemm(stream, y, tgt_emb, nullptr, out, Mr, V, 512, 512, 512, V,
       1, 1, 0, 0, 0, 0, 0, 0, 0, 1.f, 0, 1);
}

// Round 6
// 2613.344 us; speedup vs baseline: 1.6890x; 1.6890x over previous
//
#include <hip/hip_runtime.h>
#include <math.h>

typedef _Float16 f16;
typedef _Float16 f16x4 __attribute__((ext_vector_type(4)));
typedef _Float16 f16x8 __attribute__((ext_vector_type(8)));
typedef float    f32x4 __attribute__((ext_vector_type(4)));
typedef long long LL;

#define MFMA16(a,b,c) __builtin_amdgcn_mfma_f32_16x16x32_f16((a),(b),(c),0,0,0)

// ---------------------------------------------------------------------------
// embed: x[row,:] = emb[tok[row]] * sqrt(512) + sinusoidal_pe(row % S)
// ---------------------------------------------------------------------------
__global__ __launch_bounds__(256) void embed_kernel(
    float* __restrict__ x, const int* __restrict__ tok,
    const float* __restrict__ emb, int S)
{
  int row = blockIdx.x;
  int s   = row % S;
  LL  t   = tok[row];
  #pragma unroll
  for (int i = 0; i < 2; i++) {
    int d = threadIdx.x + i * 256;
    int j = d >> 1;
    float omega = (float)(j + 1) * (1.0f / 512.0f);
    float w = (float)(s + 1) * powf(10000.0f, -omega);
    float pe = (d & 1) ? cosf(w) : sinf(w);
    x[(LL)row * 512 + d] = emb[t * 512 + d] * 22.62741699796952f + pe;
  }
}

// ---------------------------------------------------------------------------
// x = LayerNorm(x + d) * g + b, rows of 512; one wave/row, 4 rows/block.
// ---------------------------------------------------------------------------
__global__ __launch_bounds__(256) void ln_kernel(
    float* __restrict__ x, const float* __restrict__ d,
    const float* __restrict__ g, const float* __restrict__ b)
{
  int lane = threadIdx.x & 63;
  LL row = (LL)blockIdx.x * 4 + (threadIdx.x >> 6);
  float* xr = x + row * 512;
  const float* dr = d + row * 512;
  float v[8];
  float s = 0.f;
  #pragma unroll
  for (int i = 0; i < 2; i++) {
    float4 a = *(const float4*)(xr + (LL)(lane + i * 64) * 4);
    float4 e = *(const float4*)(dr + (LL)(lane + i * 64) * 4);
    v[i*4+0] = a.x + e.x; v[i*4+1] = a.y + e.y;
    v[i*4+2] = a.z + e.z; v[i*4+3] = a.w + e.w;
    s += v[i*4+0] + v[i*4+1] + v[i*4+2] + v[i*4+3];
  }
  #pragma unroll
  for (int o = 32; o > 0; o >>= 1) s += __shfl_xor(s, o);
  float mean = s * (1.f / 512.f);
  float q = 0.f;
  #pragma unroll
  for (int i = 0; i < 8; i++) { float t = v[i] - mean; q += t * t; }
  #pragma unroll
  for (int o = 32; o > 0; o >>= 1) q += __shfl_xor(q, o);
  float rstd = rsqrtf(q * (1.f / 512.f) + 1e-5f);
  #pragma unroll
  for (int i = 0; i < 2; i++) {
    float4 gv = *(const float4*)(g + (LL)(lane + i * 64) * 4);
    float4 bv = *(const float4*)(b + (LL)(lane + i * 64) * 4);
    float4 o4;
    o4.x = (v[i*4+0] - mean) * rstd * gv.x + bv.x;
    o4.y = (v[i*4+1] - mean) * rstd * gv.y + bv.y;
    o4.z = (v[i*4+2] - mean) * rstd * gv.z + bv.z;
    o4.w = (v[i*4+3] - mean) * rstd * gv.w + bv.w;
    *(float4*)(xr + (LL)(lane + i * 64) * 4) = o4;
  }
}

// ---------------------------------------------------------------------------
// transpose+convert: f32 src slice [R][C] -> f16 dst [C][R].
// z picks slice; src base = s0/s1/s2 by z/nPer. One-time prep (runs per call).
// ---------------------------------------------------------------------------
__global__ __launch_bounds__(256) void tconv_kernel(
    const float* __restrict__ s0, const float* __restrict__ s1,
    const float* __restrict__ s2, f16* __restrict__ dst,
    int R, int C, int nPer, LL sStride, LL dStride)
{
  __shared__ __align__(16) f16 T[64][72];
  int z = blockIdx.z;
  const float* src = (z < nPer) ? s0 : (z < 2 * nPer ? s1 : s2);
  src += (LL)(z % nPer) * sStride;
  f16* d = dst + (LL)z * dStride;
  int rb = blockIdx.y * 64, cb = blockIdx.x * 64;
  int t = threadIdx.x;
  #pragma unroll
  for (int i = 0; i < 4; i++) {
    int u = t + i * 256; int r = u >> 4, c4 = (u & 15) << 2;
    float4 v = *(const float4*)(src + (LL)(rb + r) * C + cb + c4);
    T[c4+0][r] = (f16)v.x; T[c4+1][r] = (f16)v.y;
    T[c4+2][r] = (f16)v.z; T[c4+3][r] = (f16)v.w;
  }
  __syncthreads();
  #pragma unroll
  for (int i = 0; i < 2; i++) {
    int u = t + i * 256; int c = u >> 3, r8 = (u & 7) << 3;
    *(f16x8*)(d + (LL)(cb + c) * R + rb + r8) = *(const f16x8*)&T[c][r8];
  }
}

// ---------------------------------------------------------------------------
// GEMM: C = act((z==0?A0:A1) @ B_z^T + bias_z).  B stored [N][K] (f16 or f32).
// Tile 64x64x64, 4 waves 2x2, grid (M/64 fast, N/64, Z) for B-tile L2 reuse.
// vtMode && z==2: write transposed f16 into Vt[b][h][dh][s] (attention V).
// ---------------------------------------------------------------------------
__global__ __launch_bounds__(256) void gemm_kernel(
    const float* __restrict__ A0, const float* __restrict__ A1,
    const void* __restrict__ Bv, int bF16,
    const float* __restrict__ bias, int biasStride,
    float* __restrict__ C, f16* __restrict__ Vt,
    int K, int lda, int ldc, LL sB, LL sC, int relu, int vtMode)
{
  __shared__ __align__(16) f16 As[64][72];
  __shared__ __align__(16) f16 Bs[64][72];
  int z = blockIdx.z;
  const float* A = (z == 0) ? A0 : A1;
  int m0 = blockIdx.x * 64, n0 = blockIdx.y * 64;
  int tid = threadIdx.x, lane = tid & 63, wave = tid >> 6;
  int wr = wave >> 1, wc = wave & 1;
  int lr = lane & 15, lg = lane >> 4;
  const f16*   B16 = (const f16*)Bv + z * sB;
  const float* B32 = (const float*)Bv + z * sB;

  f32x4 acc[2][2] = {};

  for (int k0 = 0; k0 < K; k0 += 64) {
    #pragma unroll
    for (int i = 0; i < 4; i++) {
      int u = tid + i * 256; int r = u >> 4, c4 = (u & 15) << 2;
      float4 va = *(const float4*)(A + (LL)(m0 + r) * lda + k0 + c4);
      f16x4 wa = {(f16)va.x, (f16)va.y, (f16)va.z, (f16)va.w};
      *(f16x4*)&As[r][c4] = wa;
    }
    if (bF16) {
      #pragma unroll
      for (int i = 0; i < 2; i++) {
        int u = tid + i * 256; int n = u >> 3, k8 = (u & 7) << 3;
        *(f16x8*)&Bs[n][k8] = *(const f16x8*)(B16 + (LL)(n0 + n) * K + k0 + k8);
      }
    } else {
      #pragma unroll
      for (int i = 0; i < 4; i++) {
        int u = tid + i * 256; int n = u >> 4, c4 = (u & 15) << 2;
        float4 vb = *(const float4*)(B32 + (LL)(n0 + n) * K + k0 + c4);
        f16x4 wb = {(f16)vb.x, (f16)vb.y, (f16)vb.z, (f16)vb.w};
        *(f16x4*)&Bs[n][c4] = wb;
      }
    }
    __syncthreads();
    #pragma unroll
    for (int ks = 0; ks < 2; ks++) {
      int kk = ks * 32 + lg * 8;
      f16x8 a0 = *(const f16x8*)&As[wr*32 + lr][kk];
      f16x8 a1 = *(const f16x8*)&As[wr*32 + 16 + lr][kk];
      f16x8 b0 = *(const f16x8*)&Bs[wc*32 + lr][kk];
      f16x8 b1 = *(const f16x8*)&Bs[wc*32 + 16 + lr][kk];
      acc[0][0] = MFMA16(a0, b0, acc[0][0]);
      acc[0][1] = MFMA16(a0, b1, acc[0][1]);
      acc[1][0] = MFMA16(a1, b0, acc[1][0]);
      acc[1][1] = MFMA16(a1, b1, acc[1][1]);
    }
    __syncthreads();
  }

  if (vtMode && z == 2) {
    // V slice: write bias-added result transposed as f16 into Vt[b][h][dh][s]
    #pragma unroll
    for (int mf = 0; mf < 2; mf++) {
      #pragma unroll
      for (int nf = 0; nf < 2; nf++) {
        int col = n0 + wc * 32 + nf * 16 + lr;
        int h = col >> 6, dh = col & 63;
        float bv = bias[z * biasStride + col];
        int row = m0 + wr * 32 + mf * 16 + lg * 4;
        int b = row / 384, s = row - b * 384;     // 64-tiles never cross batch
        f16x4 o = {(f16)(acc[mf][nf][0] + bv), (f16)(acc[mf][nf][1] + bv),
                   (f16)(acc[mf][nf][2] + bv), (f16)(acc[mf][nf][3] + bv)};
        *(f16x4*)(Vt + ((LL)(b * 8 + h) * 64 + dh) * 384 + s) = o;
      }
    }
  } else {
    float* Cz = C + z * sC;
    #pragma unroll
    for (int mf = 0; mf < 2; mf++) {
      #pragma unroll
      for (int nf = 0; nf < 2; nf++) {
        int col = n0 + wc * 32 + nf * 16 + lr;
        float bv = bias ? bias[z * biasStride + col] : 0.f;
        int row = m0 + wr * 32 + mf * 16 + lg * 4;
        #pragma unroll
        for (int j = 0; j < 4; j++) {
          float val = acc[mf][nf][j] + bv;
          if (relu) val = fmaxf(val, 0.f);
          Cz[(LL)(row + j) * ldc + col] = val;
        }
      }
    }
  }
}

// ---------------------------------------------------------------------------
// Fused attention: out = softmax(mask(Q K^T / 8)) V  per (b,h), q-tile of 64.
// q,k: f32 [B*S][512] (head slice h). Vt: f16 [b][h][64][384]. out: f32.
// Scores kept in LDS f32 [64][396]; full-row softmax (exact, S=384 small).
// ---------------------------------------------------------------------------
__global__ __launch_bounds__(256) void attn_kernel(
    const float* __restrict__ q, const float* __restrict__ k,
    const f16* __restrict__ Vt, float* __restrict__ out, int causal)
{
  __shared__ __align__(16) f16 Qs[64][72];
  __shared__ __align__(16) f16 Ks[64][72];
  __shared__ __align__(16) f16 Vs[64][72];
  __shared__ __align__(16) float SL[64][396];

  int qt = blockIdx.x, bh = blockIdx.y;
  int b = bh >> 3, h = bh & 7;
  int tid = threadIdx.x, lane = tid & 63, wave = tid >> 6;
  int wr = wave >> 1, wc = wave & 1, lr = lane & 15, lg = lane >> 4;
  int q0 = qt * 64;
  LL base = (LL)(b * 384) * 512 + h * 64;     // (b, s=0, h, d=0) element offset

  // stage Q tile (f32 -> f16)
  #pragma unroll
  for (int i = 0; i < 4; i++) {
    int u = tid + i * 256; int r = u >> 4, c4 = (u & 15) << 2;
    float4 v = *(const float4*)(q + base + (LL)(q0 + r) * 512 + c4);
    f16x4 w = {(f16)v.x, (f16)v.y, (f16)v.z, (f16)v.w};
    *(f16x4*)&Qs[r][c4] = w;
  }
  int nkt = causal ? (qt + 1) : 6;

  // ---- QK^T into SL ----
  for (int kt = 0; kt < nkt; kt++) {
    #pragma unroll
    for (int i = 0; i < 4; i++) {
      int u = tid + i * 256; int r = u >> 4, c4 = (u & 15) << 2;
      float4 v = *(const float4*)(k + base + (LL)(kt * 64 + r) * 512 + c4);
      f16x4 w = {(f16)v.x, (f16)v.y, (f16)v.z, (f16)v.w};
      *(f16x4*)&Ks[r][c4] = w;
    }
    __syncthreads();
    f32x4 acc[2][2] = {};
    #pragma unroll
    for (int ks = 0; ks < 2; ks++) {
      int kk = ks * 32 + lg * 8;
      f16x8 a0 = *(const f16x8*)&Qs[wr*32 + lr][kk];
      f16x8 a1 = *(const f16x8*)&Qs[wr*32 + 16 + lr][kk];
      f16x8 b0 = *(const f16x8*)&Ks[wc*32 + lr][kk];
      f16x8 b1 = *(const f16x8*)&Ks[wc*32 + 16 + lr][kk];
      acc[0][0] = MFMA16(a0, b0, acc[0][0]);
      acc[0][1] = MFMA16(a0, b1, acc[0][1]);
      acc[1][0] = MFMA16(a1, b0, acc[1][0]);
      acc[1][1] = MFMA16(a1, b1, acc[1][1]);
    }
    #pragma unroll
    for (int mf = 0; mf < 2; mf++)
      #pragma unroll
      for (int nf = 0; nf < 2; nf++) {
        int col = kt * 64 + wc * 32 + nf * 16 + lr;
        int row = wr * 32 + mf * 16 + lg * 4;
        #pragma unroll
        for (int j = 0; j < 4; j++)
          SL[row + j][col] = acc[mf][nf][j] * 0.125f;
      }
    __syncthreads();
  }

  // ---- softmax: wave handles rows wave*16 .. +15 ----
  for (int rr = 0; rr < 16; rr++) {
    int r = wave * 16 + rr;
    int kmax = causal ? (q0 + r + 1) : 384;
    float vv[6];
    float m = -1e30f;
    for (int i = 0; i < nkt; i++) {
      int c = lane + i * 64;
      vv[i] = SL[r][c];
      if (c < kmax) m = fmaxf(m, vv[i]);
    }
    #pragma unroll
    for (int o = 32; o > 0; o >>= 1) m = fmaxf(m, __shfl_xor(m, o));
    float s = 0.f;
    for (int i = 0; i < nkt; i++) {
      int c = lane + i * 64;
      float e = (c < kmax) ? __expf(vv[i] - m) : 0.f;
      vv[i] = e; s += e;
    }
    #pragma unroll
    for (int o = 32; o > 0; o >>= 1) s += __shfl_xor(s, o);
    float inv = 1.f / s;
    for (int i = 0; i < nkt; i++) SL[r][lane + i * 64] = vv[i] * inv;
  }
  __syncthreads();

  // ---- PV ----
  f32x4 oacc[2][2] = {};
  for (int vt = 0; vt < nkt; vt++) {
    #pragma unroll
    for (int i = 0; i < 2; i++) {
      int u = tid + i * 256; int dh = u >> 3, s8 = (u & 7) << 3;
      *(f16x8*)&Vs[dh][s8] =
          *(const f16x8*)(Vt + ((LL)bh * 64 + dh) * 384 + vt * 64 + s8);
    }
    __syncthreads();
    #pragma unroll
    for (int ks = 0; ks < 2; ks++) {
      int sk = vt * 64 + ks * 32 + lg * 8;
      const float* p0 = &SL[wr*32 + lr][sk];
      const float* p1 = &SL[wr*32 + 16 + lr][sk];
      float4 x0 = *(const float4*)p0, x1 = *(const float4*)(p0 + 4);
      float4 y0 = *(const float4*)p1, y1 = *(const float4*)(p1 + 4);
      f16x8 pa0 = {(f16)x0.x,(f16)x0.y,(f16)x0.z,(f16)x0.w,
                   (f16)x1.x,(f16)x1.y,(f16)x1.z,(f16)x1.w};
      f16x8 pa1 = {(f16)y0.x,(f16)y0.y,(f16)y0.z,(f16)y0.w,
                   (f16)y1.x,(f16)y1.y,(f16)y1.z,(f16)y1.w};
      int kk = ks * 32 + lg * 8;
      f16x8 vb0 = *(const f16x8*)&Vs[wc*32 + lr][kk];
      f16x8 vb1 = *(const f16x8*)&Vs[wc*32 + 16 + lr][kk];
      oacc[0][0] = MFMA16(pa0, vb0, oacc[0][0]);
      oacc[0][1] = MFMA16(pa0, vb1, oacc[0][1]);
      oacc[1][0] = MFMA16(pa1, vb0, oacc[1][0]);
      oacc[1][1] = MFMA16(pa1, vb1, oacc[1][1]);
    }
    __syncthreads();
  }
  #pragma unroll
  for (int mf = 0; mf < 2; mf++)
    #pragma unroll
    for (int nf = 0; nf < 2; nf++) {
      int col = wc * 32 + nf * 16 + lr;
      int row = q0 + wr * 32 + mf * 16 + lg * 4;
      #pragma unroll
      for (int j = 0; j < 4; j++)
        out[base + (LL)(row + j) * 512 + col] = oacc[mf][nf][j];
    }
}

// ---------------------------------------------------------------------------
static inline void gemm(hipStream_t st, int M, int N, int Z,
    const float* A0, const float* A1, const void* B, int bF16,
    const float* bias, int biasStride, float* C, f16* Vt,
    int K, int lda, int ldc, LL sB, LL sC, int relu, int vtMode)
{
  dim3 g(M / 64, N / 64, Z);
  gemm_kernel<<<g, 256, 0, st>>>(A0, A1, B, bF16, bias, biasStride, C, Vt,
                                 K, lda, ldc, sB, sC, relu, vtMode);
}

extern "C" void kernel_launch(void* const* d_in, const int* in_sizes, int n_in,
                              void* d_out, int out_size, void* d_ws, size_t ws_size,
                              hipStream_t stream)
{
  (void)in_sizes; (void)n_in; (void)out_size; (void)ws_size;
  const int*   src     = (const int*)d_in[0];
  const int*   tgt     = (const int*)d_in[1];
  const float* src_emb = (const float*)d_in[2];
  const float* tgt_emb = (const float*)d_in[3];
  const float* eaw = (const float*)d_in[4];
  const float* eab = (const float*)d_in[5];
  const float* ef1 = (const float*)d_in[6];
  const float* eb1 = (const float*)d_in[7];
  const float* ef2 = (const float*)d_in[8];
  const float* eb2 = (const float*)d_in[9];
  const float* elg = (const float*)d_in[10];
  const float* elb = (const float*)d_in[11];
  const float* dmw = (const float*)d_in[12];
  const float* dmb = (const float*)d_in[13];
  const float* dsw = (const float*)d_in[14];
  const float* dsb = (const float*)d_in[15];
  const float* df1 = (const float*)d_in[16];
  const float* db1 = (const float*)d_in[17];
  const float* df2 = (const float*)d_in[18];
  const float* db2 = (const float*)d_in[19];
  const float* dlg = (const float*)d_in[20];
  const float* dlb = (const float*)d_in[21];
  float* out = (float*)d_out;

  const int S = 384, D = 512, F = 2048, Lc = 6, V = 32000;
  const int Mr = 1536;
  const LL  NX = (LL)Mr * D;            // 786432
  const LL  DD = (LL)D * D;             // 262144
  const LL  FD = (LL)D * F;             // 1048576

  float* ws   = (float*)d_ws;
  float* x    = ws;                     // enc state [Mr][512]
  float* y    = x + NX;                 // dec state
  float* qb   = y + NX;                 // q proj    [Mr][512]
  float* kb   = qb + NX;                // k proj    [Mr][512]  (= qb + sC)
  float* sc   = kb + NX;                // ff mid    [Mr][2048]
  float* t0   = sc + (LL)Mr * F;        // attn out
  float* t1   = t0 + NX;                // proj out
  f16*   Vt   = (f16*)(t1 + NX);        // V^T f16 [B][H][64][384] = 786432 f16
  f16*   wAT  = Vt + NX;                // attn W^T: 72 slices x DD f16
  f16*   wF1  = wAT + 72 * DD;          // ff1 W^T: 12 x [2048][512] f16
  f16*   wF2  = wF1 + 12 * FD;          // ff2 W^T: 12 x [512][2048] f16
  // total ws ≈ 124 MB

  // ---- prep: transpose+convert all weights to f16 [N][K] ----
  tconv_kernel<<<dim3(8, 8, 72), 256, 0, stream>>>(eaw, dmw, dsw, wAT, 512, 512, 24, DD, DD);
  tconv_kernel<<<dim3(32, 8, 12), 256, 0, stream>>>(ef1, df1, df1, wF1, 512, 2048, 6, FD, FD);
  tconv_kernel<<<dim3(8, 32, 12), 256, 0, stream>>>(ef2, df2, df2, wF2, 2048, 512, 6, FD, FD);

  // ---------------- encoder ----------------
  embed_kernel<<<Mr, 256, 0, stream>>>(x, src, src_emb, S);
  for (int i = 0; i < Lc; i++) {
    const f16* W = wAT + (LL)i * 4 * DD;
    const float* bia = eab + (LL)i * 4 * D;
    gemm(stream, Mr, 512, 3, x, x, W, 1, bia, D, qb, Vt, 512, 512, 512, DD, NX, 0, 1);
    attn_kernel<<<dim3(6, 32), 256, 0, stream>>>(qb, kb, Vt, t0, 1);  // enc is causal (quirk)
    gemm(stream, Mr, 512, 1, t0, t0, W + 3 * DD, 1, bia + 3 * D, 0, t1, nullptr,
         512, 512, 512, 0, 0, 0, 0);
    ln_kernel<<<Mr / 4, 256, 0, stream>>>(x, t1, elg, elb);
    gemm(stream, Mr, F, 1, x, x, wF1 + (LL)i * FD, 1, eb1 + (LL)i * F, 0, sc, nullptr,
         512, 512, F, 0, 0, 1, 0);
    gemm(stream, Mr, 512, 1, sc, sc, wF2 + (LL)i * FD, 1, eb2 + (LL)i * D, 0, t1, nullptr,
         F, F, 512, 0, 0, 1, 0);
    ln_kernel<<<Mr / 4, 256, 0, stream>>>(x, t1, elg, elb);
  }

  // ---------------- decoder ----------------
  embed_kernel<<<Mr, 256, 0, stream>>>(y, tgt, tgt_emb, S);
  for (int i = 0; i < Lc; i++) {
    // memory attention (not causal): q from y; k,v from enc output x
    const f16* Wm = wAT + (24 + (LL)i * 4) * DD;
    const float* bm = dmb + (LL)i * 4 * D;
    gemm(stream, Mr, 512, 3, y, x, Wm, 1, bm, D, qb, Vt, 512, 512, 512, DD, NX, 0, 1);
    attn_kernel<<<dim3(6, 32), 256, 0, stream>>>(qb, kb, Vt, t0, 0);
    gemm(stream, Mr, 512, 1, t0, t0, Wm + 3 * DD, 1, bm + 3 * D, 0, t1, nullptr,
         512, 512, 512, 0, 0, 0, 0);
    ln_kernel<<<Mr / 4, 256, 0, stream>>>(y, t1, dlg, dlb);
    // self attention (causal)
    const f16* Ws = wAT + (48 + (LL)i * 4) * DD;
    const float* bs = dsb + (LL)i * 4 * D;
    gemm(stream, Mr, 512, 3, y, y, Ws, 1, bs, D, qb, Vt, 512, 512, 512, DD, NX, 0, 1);
    attn_kernel<<<dim3(6, 32), 256, 0, stream>>>(qb, kb, Vt, t0, 1);
    gemm(stream, Mr, 512, 1, t0, t0, Ws + 3 * DD, 1, bs + 3 * D, 0, t1, nullptr,
         512, 512, 512, 0, 0, 0, 0);
    ln_kernel<<<Mr / 4, 256, 0, stream>>>(y, t1, dlg, dlb);
    // ff
    gemm(stream, Mr, F, 1, y, y, wF1 + (6 + (LL)i) * FD, 1, db1 + (LL)i * F, 0, sc, nullptr,
         512, 512, F, 0, 0, 1, 0);
    gemm(stream, Mr, 512, 1, sc, sc, wF2 + (6 + (LL)i) * FD, 1, db2 + (LL)i * D, 0, t1, nullptr,
         F, F, 512, 0, 0, 1, 0);
    ln_kernel<<<Mr / 4, 256, 0, stream>>>(y, t1, dlg, dlb);
  }

  // ---------------- unembed: out = y @ tgt_emb^T (tgt_emb already [N][K]) ----
  gemm(stream, Mr, V, 1, y, y, tgt_emb, 0, nullptr, 0, out, nullptr,
       512, 512, V, 0, 0, 0, 0);
}

// Round 7
// 1947.988 us; speedup vs baseline: 2.2660x; 1.3416x over previous
//
#include <hip/hip_runtime.h>
#include <math.h>

typedef _Float16 f16;
typedef _Float16 f16x4 __attribute__((ext_vector_type(4)));
typedef _Float16 f16x8 __attribute__((ext_vector_type(8)));
typedef float    f32x4 __attribute__((ext_vector_type(4)));
typedef long long LL;

#define MFMA16(a,b,c) __builtin_amdgcn_mfma_f32_16x16x32_f16((a),(b),(c),0,0,0)

// ---------------------------------------------------------------------------
// embed: x = emb[tok]*sqrt(512) + pe;  writes f32 state + f16 copy
// ---------------------------------------------------------------------------
__global__ __launch_bounds__(256) void embed_kernel(
    float* __restrict__ x, f16* __restrict__ xh, const int* __restrict__ tok,
    const float* __restrict__ emb, int S)
{
  int row = blockIdx.x;
  int s   = row % S;
  LL  t   = tok[row];
  #pragma unroll
  for (int i = 0; i < 2; i++) {
    int d = threadIdx.x + i * 256;
    int j = d >> 1;
    float omega = (float)(j + 1) * (1.0f / 512.0f);
    float w = (float)(s + 1) * powf(10000.0f, -omega);
    float pe = (d & 1) ? cosf(w) : sinf(w);
    float v = emb[t * 512 + d] * 22.62741699796952f + pe;
    x[(LL)row * 512 + d]  = v;
    xh[(LL)row * 512 + d] = (f16)v;
  }
}

// ---------------------------------------------------------------------------
// x = LN(x + d)*g + b (d is f16); writes f32 state + f16 copy
// ---------------------------------------------------------------------------
__global__ __launch_bounds__(256) void ln_kernel(
    float* __restrict__ x, f16* __restrict__ xh, const f16* __restrict__ d,
    const float* __restrict__ g, const float* __restrict__ b)
{
  int lane = threadIdx.x & 63;
  LL row = (LL)blockIdx.x * 4 + (threadIdx.x >> 6);
  float* xr = x + row * 512;
  f16*  xhr = xh + row * 512;
  const f16* dr = d + row * 512;
  float v[8];
  float s = 0.f;
  #pragma unroll
  for (int i = 0; i < 2; i++) {
    float4 a = *(const float4*)(xr + (LL)(lane + i * 64) * 4);
    f16x4  e = *(const f16x4*)(dr + (LL)(lane + i * 64) * 4);
    v[i*4+0] = a.x + (float)e[0]; v[i*4+1] = a.y + (float)e[1];
    v[i*4+2] = a.z + (float)e[2]; v[i*4+3] = a.w + (float)e[3];
    s += v[i*4+0] + v[i*4+1] + v[i*4+2] + v[i*4+3];
  }
  #pragma unroll
  for (int o = 32; o > 0; o >>= 1) s += __shfl_xor(s, o);
  float mean = s * (1.f / 512.f);
  float q = 0.f;
  #pragma unroll
  for (int i = 0; i < 8; i++) { float t = v[i] - mean; q += t * t; }
  #pragma unroll
  for (int o = 32; o > 0; o >>= 1) q += __shfl_xor(q, o);
  float rstd = rsqrtf(q * (1.f / 512.f) + 1e-5f);
  #pragma unroll
  for (int i = 0; i < 2; i++) {
    float4 gv = *(const float4*)(g + (LL)(lane + i * 64) * 4);
    float4 bv = *(const float4*)(b + (LL)(lane + i * 64) * 4);
    float4 o4;
    o4.x = (v[i*4+0] - mean) * rstd * gv.x + bv.x;
    o4.y = (v[i*4+1] - mean) * rstd * gv.y + bv.y;
    o4.z = (v[i*4+2] - mean) * rstd * gv.z + bv.z;
    o4.w = (v[i*4+3] - mean) * rstd * gv.w + bv.w;
    *(float4*)(xr + (LL)(lane + i * 64) * 4) = o4;
    f16x4 h4 = {(f16)o4.x, (f16)o4.y, (f16)o4.z, (f16)o4.w};
    *(f16x4*)(xhr + (LL)(lane + i * 64) * 4) = h4;
  }
}

// ---------------------------------------------------------------------------
// transpose+convert: f32 [R][C] slice -> f16 [C][R]  (weights, prep)
// ---------------------------------------------------------------------------
__global__ __launch_bounds__(256) void tconv_kernel(
    const float* __restrict__ s0, const float* __restrict__ s1,
    const float* __restrict__ s2, f16* __restrict__ dst,
    int R, int C, int nPer, LL sStride, LL dStride)
{
  __shared__ __align__(16) f16 T[64][72];
  int z = blockIdx.z;
  const float* src = (z < nPer) ? s0 : (z < 2 * nPer ? s1 : s2);
  src += (LL)(z % nPer) * sStride;
  f16* d = dst + (LL)z * dStride;
  int rb = blockIdx.y * 64, cb = blockIdx.x * 64;
  int t = threadIdx.x;
  #pragma unroll
  for (int i = 0; i < 4; i++) {
    int u = t + i * 256; int r = u >> 4, c4 = (u & 15) << 2;
    float4 v = *(const float4*)(src + (LL)(rb + r) * C + cb + c4);
    T[c4+0][r] = (f16)v.x; T[c4+1][r] = (f16)v.y;
    T[c4+2][r] = (f16)v.z; T[c4+3][r] = (f16)v.w;
  }
  __syncthreads();
  #pragma unroll
  for (int i = 0; i < 2; i++) {
    int u = t + i * 256; int c = u >> 3, r8 = (u & 7) << 3;
    *(f16x8*)(d + (LL)(cb + c) * R + rb + r8) = *(const f16x8*)&T[c][r8];
  }
}

// ---------------------------------------------------------------------------
// elementwise f32 -> f16 (tgt_emb pre-convert; 2048 elems/block)
// ---------------------------------------------------------------------------
__global__ __launch_bounds__(256) void cvt_kernel(
    const float* __restrict__ s, f16* __restrict__ d)
{
  LL i = ((LL)blockIdx.x * 256 + threadIdx.x) * 8;
  float4 a = *(const float4*)(s + i), b = *(const float4*)(s + i + 4);
  f16x8 o = {(f16)a.x,(f16)a.y,(f16)a.z,(f16)a.w,
             (f16)b.x,(f16)b.y,(f16)b.z,(f16)b.w};
  *(f16x8*)(d + i) = o;
}

// ---------------------------------------------------------------------------
// GEMM: out = act((z==0?A0:A1) @ B_z^T + bias_z), A/B f16 [.][K].
// 64x64x64 tile, 4 waves, reg-staged DOUBLE-BUFFERED K-loop (1 barrier/step).
// Output: f32 C (ldc) or f16 Ch (ldch, +z*sCh); vtMode&&z==2 -> Vt transposed.
// ---------------------------------------------------------------------------
__global__ __launch_bounds__(256) void gemm_kernel(
    const f16* __restrict__ A0, const f16* __restrict__ A1,
    const f16* __restrict__ B, const float* __restrict__ bias, int biasStride,
    float* __restrict__ C, f16* __restrict__ Ch, f16* __restrict__ Vt,
    int K, int ldc, int ldch, LL sB, LL sCh, int relu, int vtMode)
{
  __shared__ __align__(16) f16 As[2][64][72];
  __shared__ __align__(16) f16 Bs[2][64][72];
  int z = blockIdx.z;
  const f16* A  = (z == 0) ? A0 : A1;
  const f16* Bz = B + z * sB;
  int m0 = blockIdx.x * 64, n0 = blockIdx.y * 64;
  int tid = threadIdx.x, lane = tid & 63, wave = tid >> 6;
  int wr = wave >> 1, wc = wave & 1, lr = lane & 15, lg = lane >> 4;
  int r0 = tid >> 3, k80 = (tid & 7) << 3;   // thread stages rows r0, r0+32

  f32x4 acc[2][2] = {};
  f16x8 ra0, ra1, rb0, rb1;

  // prologue: tile 0 -> buf 0
  ra0 = *(const f16x8*)(A  + (LL)(m0 + r0)      * K + k80);
  ra1 = *(const f16x8*)(A  + (LL)(m0 + r0 + 32) * K + k80);
  rb0 = *(const f16x8*)(Bz + (LL)(n0 + r0)      * K + k80);
  rb1 = *(const f16x8*)(Bz + (LL)(n0 + r0 + 32) * K + k80);
  *(f16x8*)&As[0][r0][k80] = ra0; *(f16x8*)&As[0][r0+32][k80] = ra1;
  *(f16x8*)&Bs[0][r0][k80] = rb0; *(f16x8*)&Bs[0][r0+32][k80] = rb1;

  int nt = K >> 6;
  for (int t = 0; t < nt; t++) {
    int cur = t & 1;
    if (t + 1 < nt) {                    // issue next-tile loads (latency hides)
      int k0 = (t + 1) << 6;
      ra0 = *(const f16x8*)(A  + (LL)(m0 + r0)      * K + k0 + k80);
      ra1 = *(const f16x8*)(A  + (LL)(m0 + r0 + 32) * K + k0 + k80);
      rb0 = *(const f16x8*)(Bz + (LL)(n0 + r0)      * K + k0 + k80);
      rb1 = *(const f16x8*)(Bz + (LL)(n0 + r0 + 32) * K + k0 + k80);
    }
    __syncthreads();                     // buf[cur] writes visible
    #pragma unroll
    for (int ks = 0; ks < 2; ks++) {
      int kk = ks * 32 + lg * 8;
      f16x8 a0 = *(const f16x8*)&As[cur][wr*32 + lr][kk];
      f16x8 a1 = *(const f16x8*)&As[cur][wr*32 + 16 + lr][kk];
      f16x8 b0 = *(const f16x8*)&Bs[cur][wc*32 + lr][kk];
      f16x8 b1 = *(const f16x8*)&Bs[cur][wc*32 + 16 + lr][kk];
      acc[0][0] = MFMA16(a0, b0, acc[0][0]);
      acc[0][1] = MFMA16(a0, b1, acc[0][1]);
      acc[1][0] = MFMA16(a1, b0, acc[1][0]);
      acc[1][1] = MFMA16(a1, b1, acc[1][1]);
    }
    if (t + 1 < nt) {                    // write other buffer (no barrier needed)
      int nx = cur ^ 1;
      *(f16x8*)&As[nx][r0][k80] = ra0; *(f16x8*)&As[nx][r0+32][k80] = ra1;
      *(f16x8*)&Bs[nx][r0][k80] = rb0; *(f16x8*)&Bs[nx][r0+32][k80] = rb1;
    }
  }

  if (vtMode && z == 2) {
    #pragma unroll
    for (int mf = 0; mf < 2; mf++)
      #pragma unroll
      for (int nf = 0; nf < 2; nf++) {
        int col = n0 + wc * 32 + nf * 16 + lr;
        int h = col >> 6, dh = col & 63;
        float bv = bias[z * biasStride + col];
        int row = m0 + wr * 32 + mf * 16 + lg * 4;
        int b = row / 384, s = row - b * 384;   // 64-tiles never cross batch
        f16x4 o = {(f16)(acc[mf][nf][0] + bv), (f16)(acc[mf][nf][1] + bv),
                   (f16)(acc[mf][nf][2] + bv), (f16)(acc[mf][nf][3] + bv)};
        *(f16x4*)(Vt + ((LL)(b * 8 + h) * 64 + dh) * 384 + s) = o;
      }
  } else if (Ch) {
    f16* Cz = Ch + z * sCh;
    #pragma unroll
    for (int mf = 0; mf < 2; mf++)
      #pragma unroll
      for (int nf = 0; nf < 2; nf++) {
        int col = n0 + wc * 32 + nf * 16 + lr;
        float bv = bias ? bias[z * biasStride + col] : 0.f;
        int row = m0 + wr * 32 + mf * 16 + lg * 4;
        #pragma unroll
        for (int j = 0; j < 4; j++) {
          float val = acc[mf][nf][j] + bv;
          if (relu) val = fmaxf(val, 0.f);
          Cz[(LL)(row + j) * ldch + col] = (f16)val;
        }
      }
  } else {
    #pragma unroll
    for (int mf = 0; mf < 2; mf++)
      #pragma unroll
      for (int nf = 0; nf < 2; nf++) {
        int col = n0 + wc * 32 + nf * 16 + lr;
        float bv = bias ? bias[z * biasStride + col] : 0.f;
        int row = m0 + wr * 32 + mf * 16 + lg * 4;
        #pragma unroll
        for (int j = 0; j < 4; j++) {
          float val = acc[mf][nf][j] + bv;
          if (relu) val = fmaxf(val, 0.f);
          C[(LL)(row + j) * ldc + col] = val;
        }
      }
  }
}

// ---------------------------------------------------------------------------
// Fused attention, f16 in/out, double-buffered K and V tiles.
// q,k: f16 [B*S][512]; Vt: f16 [b][h][64][384]; out: f16 [B*S][512].
// ---------------------------------------------------------------------------
__global__ __launch_bounds__(256) void attn_kernel(
    const f16* __restrict__ q, const f16* __restrict__ k,
    const f16* __restrict__ Vt, f16* __restrict__ out, int causal)
{
  __shared__ __align__(16) f16 Qs[64][72];
  __shared__ __align__(16) f16 Ks[2][64][72];
  __shared__ __align__(16) f16 Vs[2][64][72];
  __shared__ __align__(16) float SL[64][396];   // total LDS = 144 KiB

  int qt = blockIdx.x, bh = blockIdx.y;
  int b = bh >> 3, h = bh & 7;
  int tid = threadIdx.x, lane = tid & 63, wave = tid >> 6;
  int wr = wave >> 1, wc = wave & 1, lr = lane & 15, lg = lane >> 4;
  int q0 = qt * 64;
  LL base = (LL)(b * 384) * 512 + h * 64;
  int r0 = tid >> 3, k80 = (tid & 7) << 3;

  // stage Q (pure f16 copy)
  *(f16x8*)&Qs[r0][k80]    = *(const f16x8*)(q + base + (LL)(q0 + r0)      * 512 + k80);
  *(f16x8*)&Qs[r0+32][k80] = *(const f16x8*)(q + base + (LL)(q0 + r0 + 32) * 512 + k80);
  int nkt = causal ? (qt + 1) : 6;

  // ---- QK^T (K double-buffered, 1 barrier/tile) ----
  f16x8 rk0, rk1;
  rk0 = *(const f16x8*)(k + base + (LL)(r0)      * 512 + k80);
  rk1 = *(const f16x8*)(k + base + (LL)(r0 + 32) * 512 + k80);
  *(f16x8*)&Ks[0][r0][k80] = rk0; *(f16x8*)&Ks[0][r0+32][k80] = rk1;
  for (int kt = 0; kt < nkt; kt++) {
    int cur = kt & 1;
    if (kt + 1 < nkt) {
      rk0 = *(const f16x8*)(k + base + (LL)((kt+1)*64 + r0)      * 512 + k80);
      rk1 = *(const f16x8*)(k + base + (LL)((kt+1)*64 + r0 + 32) * 512 + k80);
    }
    __syncthreads();
    f32x4 acc[2][2] = {};
    #pragma unroll
    for (int ks = 0; ks < 2; ks++) {
      int kk = ks * 32 + lg * 8;
      f16x8 a0 = *(const f16x8*)&Qs[wr*32 + lr][kk];
      f16x8 a1 = *(const f16x8*)&Qs[wr*32 + 16 + lr][kk];
      f16x8 b0 = *(const f16x8*)&Ks[cur][wc*32 + lr][kk];
      f16x8 b1 = *(const f16x8*)&Ks[cur][wc*32 + 16 + lr][kk];
      acc[0][0] = MFMA16(a0, b0, acc[0][0]);
      acc[0][1] = MFMA16(a0, b1, acc[0][1]);
      acc[1][0] = MFMA16(a1, b0, acc[1][0]);
      acc[1][1] = MFMA16(a1, b1, acc[1][1]);
    }
    #pragma unroll
    for (int mf = 0; mf < 2; mf++)
      #pragma unroll
      for (int nf = 0; nf < 2; nf++) {
        int col = kt * 64 + wc * 32 + nf * 16 + lr;
        int row = wr * 32 + mf * 16 + lg * 4;
        #pragma unroll
        for (int j = 0; j < 4; j++)
          SL[row + j][col] = acc[mf][nf][j] * 0.125f;
      }
    if (kt + 1 < nkt) {
      int nx = cur ^ 1;
      *(f16x8*)&Ks[nx][r0][k80] = rk0; *(f16x8*)&Ks[nx][r0+32][k80] = rk1;
    }
  }
  __syncthreads();

  // ---- softmax: wave handles rows wave*16..+15 ----
  for (int rr = 0; rr < 16; rr++) {
    int r = wave * 16 + rr;
    int kmax = causal ? (q0 + r + 1) : 384;
    float vv[6];
    float m = -1e30f;
    for (int i = 0; i < nkt; i++) {
      int c = lane + i * 64;
      vv[i] = SL[r][c];
      if (c < kmax) m = fmaxf(m, vv[i]);
    }
    #pragma unroll
    for (int o = 32; o > 0; o >>= 1) m = fmaxf(m, __shfl_xor(m, o));
    float s = 0.f;
    for (int i = 0; i < nkt; i++) {
      int c = lane + i * 64;
      float e = (c < kmax) ? __expf(vv[i] - m) : 0.f;
      vv[i] = e; s += e;
    }
    #pragma unroll
    for (int o = 32; o > 0; o >>= 1) s += __shfl_xor(s, o);
    float inv = 1.f / s;
    for (int i = 0; i < nkt; i++) SL[r][lane + i * 64] = vv[i] * inv;
  }

  // ---- PV (V double-buffered; first barrier also fences softmax) ----
  f32x4 oacc[2][2] = {};
  f16x8 rv0, rv1;
  rv0 = *(const f16x8*)(Vt + ((LL)bh * 64 + r0)      * 384 + k80);
  rv1 = *(const f16x8*)(Vt + ((LL)bh * 64 + r0 + 32) * 384 + k80);
  *(f16x8*)&Vs[0][r0][k80] = rv0; *(f16x8*)&Vs[0][r0+32][k80] = rv1;
  for (int vt = 0; vt < nkt; vt++) {
    int cur = vt & 1;
    if (vt + 1 < nkt) {
      rv0 = *(const f16x8*)(Vt + ((LL)bh * 64 + r0)      * 384 + (vt+1)*64 + k80);
      rv1 = *(const f16x8*)(Vt + ((LL)bh * 64 + r0 + 32) * 384 + (vt+1)*64 + k80);
    }
    __syncthreads();
    #pragma unroll
    for (int ks = 0; ks < 2; ks++) {
      int sk = vt * 64 + ks * 32 + lg * 8;
      const float* p0 = &SL[wr*32 + lr][sk];
      const float* p1 = &SL[wr*32 + 16 + lr][sk];
      float4 x0 = *(const float4*)p0, x1 = *(const float4*)(p0 + 4);
      float4 y0 = *(const float4*)p1, y1 = *(const float4*)(p1 + 4);
      f16x8 pa0 = {(f16)x0.x,(f16)x0.y,(f16)x0.z,(f16)x0.w,
                   (f16)x1.x,(f16)x1.y,(f16)x1.z,(f16)x1.w};
      f16x8 pa1 = {(f16)y0.x,(f16)y0.y,(f16)y0.z,(f16)y0.w,
                   (f16)y1.x,(f16)y1.y,(f16)y1.z,(f16)y1.w};
      int kk = ks * 32 + lg * 8;
      f16x8 vb0 = *(const f16x8*)&Vs[cur][wc*32 + lr][kk];
      f16x8 vb1 = *(const f16x8*)&Vs[cur][wc*32 + 16 + lr][kk];
      oacc[0][0] = MFMA16(pa0, vb0, oacc[0][0]);
      oacc[0][1] = MFMA16(pa0, vb1, oacc[0][1]);
      oacc[1][0] = MFMA16(pa1, vb0, oacc[1][0]);
      oacc[1][1] = MFMA16(pa1, vb1, oacc[1][1]);
    }
    if (vt + 1 < nkt) {
      int nx = cur ^ 1;
      *(f16x8*)&Vs[nx][r0][k80] = rv0; *(f16x8*)&Vs[nx][r0+32][k80] = rv1;
    }
  }
  #pragma unroll
  for (int mf = 0; mf < 2; mf++)
    #pragma unroll
    for (int nf = 0; nf < 2; nf++) {
      int col = wc * 32 + nf * 16 + lr;
      int row = q0 + wr * 32 + mf * 16 + lg * 4;
      #pragma unroll
      for (int j = 0; j < 4; j++)
        out[base + (LL)(row + j) * 512 + col] = (f16)oacc[mf][nf][j];
    }
}

// ---------------------------------------------------------------------------
static inline void gemm(hipStream_t st, int M, int N, int Z,
    const f16* A0, const f16* A1, const f16* B, const float* bias, int biasStride,
    float* C, f16* Ch, f16* Vt, int K, int ldc, int ldch, LL sB, LL sCh,
    int relu, int vtMode)
{
  dim3 g(M / 64, N / 64, Z);
  gemm_kernel<<<g, 256, 0, st>>>(A0, A1, B, bias, biasStride, C, Ch, Vt,
                                 K, ldc, ldch, sB, sCh, relu, vtMode);
}

extern "C" void kernel_launch(void* const* d_in, const int* in_sizes, int n_in,
                              void* d_out, int out_size, void* d_ws, size_t ws_size,
                              hipStream_t stream)
{
  (void)in_sizes; (void)n_in; (void)out_size; (void)ws_size;
  const int*   src     = (const int*)d_in[0];
  const int*   tgt     = (const int*)d_in[1];
  const float* src_emb = (const float*)d_in[2];
  const float* tgt_emb = (const float*)d_in[3];
  const float* eaw = (const float*)d_in[4];
  const float* eab = (const float*)d_in[5];
  const float* ef1 = (const float*)d_in[6];
  const float* eb1 = (const float*)d_in[7];
  const float* ef2 = (const float*)d_in[8];
  const float* eb2 = (const float*)d_in[9];
  const float* elg = (const float*)d_in[10];
  const float* elb = (const float*)d_in[11];
  const float* dmw = (const float*)d_in[12];
  const float* dmb = (const float*)d_in[13];
  const float* dsw = (const float*)d_in[14];
  const float* dsb = (const float*)d_in[15];
  const float* df1 = (const float*)d_in[16];
  const float* db1 = (const float*)d_in[17];
  const float* df2 = (const float*)d_in[18];
  const float* db2 = (const float*)d_in[19];
  const float* dlg = (const float*)d_in[20];
  const float* dlb = (const float*)d_in[21];
  float* out = (float*)d_out;

  const int S = 384, D = 512, F = 2048, Lc = 6, V = 32000;
  const int Mr = 1536;
  const LL  NX = (LL)Mr * D;            // 786432
  const LL  DD = (LL)D * D;             // 262144
  const LL  FD = (LL)D * F;             // 1048576

  float* ws = (float*)d_ws;
  float* x  = ws;                       // enc state f32 [Mr][512]
  float* y  = x + NX;                   // dec state f32
  f16* xh   = (f16*)(y + NX);           // enc state f16
  f16* yh   = xh + NX;                  // dec state f16
  f16* qh   = yh + NX;                  // q proj f16 (z=0)
  f16* kh   = qh + NX;                  // k proj f16 (z=1, = qh + NX)
  f16* t0h  = kh + NX;                  // attn out f16
  f16* t1h  = t0h + NX;                 // proj/ff out f16
  f16* sch  = t1h + NX;                 // ff mid f16 [Mr][2048] = 4*NX
  f16* Vt   = sch + 4 * NX;             // V^T f16 [B][H][64][384]
  f16* wAT  = Vt + NX;                  // attn W^T: 72 x DD
  f16* wF1  = wAT + 72 * DD;            // ff1 W^T: 12 x FD
  f16* wF2  = wF1 + 12 * FD;            // ff2 W^T: 12 x FD
  f16* temb16 = wF2 + 12 * FD;          // tgt_emb f16 [V][512]
  // total ws ≈ 144 MB

  // ---- prep ----
  tconv_kernel<<<dim3(8, 8, 72), 256, 0, stream>>>(eaw, dmw, dsw, wAT, 512, 512, 24, DD, DD);
  tconv_kernel<<<dim3(32, 8, 12), 256, 0, stream>>>(ef1, df1, df1, wF1, 512, 2048, 6, FD, FD);
  tconv_kernel<<<dim3(8, 32, 12), 256, 0, stream>>>(ef2, df2, df2, wF2, 2048, 512, 6, FD, FD);
  cvt_kernel<<<(V * D) / 2048, 256, 0, stream>>>(tgt_emb, temb16);

  // ---------------- encoder ----------------
  embed_kernel<<<Mr, 256, 0, stream>>>(x, xh, src, src_emb, S);
  for (int i = 0; i < Lc; i++) {
    const f16* W = wAT + (LL)i * 4 * DD;
    const float* bia = eab + (LL)i * 4 * D;
    gemm(stream, Mr, 512, 3, xh, xh, W, bia, D, nullptr, qh, Vt, 512, 0, 512, DD, NX, 0, 1);
    attn_kernel<<<dim3(6, 32), 256, 0, stream>>>(qh, kh, Vt, t0h, 1);  // enc causal (quirk)
    gemm(stream, Mr, 512, 1, t0h, t0h, W + 3 * DD, bia + 3 * D, 0, nullptr, t1h, nullptr,
         512, 0, 512, 0, 0, 0, 0);
    ln_kernel<<<Mr / 4, 256, 0, stream>>>(x, xh, t1h, elg, elb);
    gemm(stream, Mr, F, 1, xh, xh, wF1 + (LL)i * FD, eb1 + (LL)i * F, 0, nullptr, sch, nullptr,
         512, 0, F, 0, 0, 1, 0);
    gemm(stream, Mr, 512, 1, sch, sch, wF2 + (LL)i * FD, eb2 + (LL)i * D, 0, nullptr, t1h, nullptr,
         F, 0, 512, 0, 0, 1, 0);
    ln_kernel<<<Mr / 4, 256, 0, stream>>>(x, xh, t1h, elg, elb);
  }

  // ---------------- decoder ----------------
  embed_kernel<<<Mr, 256, 0, stream>>>(y, yh, tgt, tgt_emb, S);
  for (int i = 0; i < Lc; i++) {
    // memory attention (not causal): q from y; k,v from enc output xh
    const f16* Wm = wAT + (24 + (LL)i * 4) * DD;
    const float* bm = dmb + (LL)i * 4 * D;
    gemm(stream, Mr, 512, 3, yh, xh, Wm, bm, D, nullptr, qh, Vt, 512, 0, 512, DD, NX, 0, 1);
    attn_kernel<<<dim3(6, 32), 256, 0, stream>>>(qh, kh, Vt, t0h, 0);
    gemm(stream, Mr, 512, 1, t0h, t0h, Wm + 3 * DD, bm + 3 * D, 0, nullptr, t1h, nullptr,
         512, 0, 512, 0, 0, 0, 0);
    ln_kernel<<<Mr / 4, 256, 0, stream>>>(y, yh, t1h, dlg, dlb);
    // self attention (causal)
    const f16* Ws = wAT + (48 + (LL)i * 4) * DD;
    const float* bs = dsb + (LL)i * 4 * D;
    gemm(stream, Mr, 512, 3, yh, yh, Ws, bs, D, nullptr, qh, Vt, 512, 0, 512, DD, NX, 0, 1);
    attn_kernel<<<dim3(6, 32), 256, 0, stream>>>(qh, kh, Vt, t0h, 1);
    gemm(stream, Mr, 512, 1, t0h, t0h, Ws + 3 * DD, bs + 3 * D, 0, nullptr, t1h, nullptr,
         512, 0, 512, 0, 0, 0, 0);
    ln_kernel<<<Mr / 4, 256, 0, stream>>>(y, yh, t1h, dlg, dlb);
    // ff
    gemm(stream, Mr, F, 1, yh, yh, wF1 + (6 + (LL)i) * FD, db1 + (LL)i * F, 0, nullptr, sch, nullptr,
         512, 0, F, 0, 0, 1, 0);
    gemm(stream, Mr, 512, 1, sch, sch, wF2 + (6 + (LL)i) * FD, db2 + (LL)i * D, 0, nullptr, t1h, nullptr,
         F, 0, 512, 0, 0, 1, 0);
    ln_kernel<<<Mr / 4, 256, 0, stream>>>(y, yh, t1h, dlg, dlb);
  }

  // ---------------- unembed: out = yh @ temb16^T (f32 out) ----------------
  gemm(stream, Mr, V, 1, yh, yh, temb16, nullptr, 0, out, nullptr, nullptr,
       512, V, 0, 0, 0, 0, 0);
}